// Round 1
// baseline (722.654 us; speedup 1.0000x reference)
//
#include <hip/hip_runtime.h>
#include <math.h>

// Problem constants
#define BB 16
#define TT 2048
#define CC 512
#define GG 2
#define DD 256      // C/G
#define VV 320
#define DT (DD*TT)             // 524288 elements per (b,g) group-norm slab
#define NOUT ((size_t)BB*TT*CC) // 16777216

// Workspace layout (bytes)
#define OFF_H      0ULL
#define SZ_H       ((size_t)BB*GG*TT*DD*4)          // 67108864
#define OFF_PART   (OFF_H + SZ_H)                    // 4096 blocks * 2 doubles = 65536
#define OFF_MUSIG  (OFF_PART + 4096ULL*2*8)          // 32 * 2 floats
#define OFF_ESQ    (OFF_MUSIG + 32ULL*2*4)           // G*V floats
#define OFF_CNT    (OFF_ESQ + (size_t)GG*VV*4)       // G*V u32
#define OFF_LOSS   (OFF_CNT + (size_t)GG*VV*4)       // 1 float
#define OFF_EMBT   67180032ULL                        // 256-aligned; G*D*V floats = 655360
// total ws usage: 67835392 bytes (~64.7 MiB)

__global__ __launch_bounds__(256) void k_init(unsigned* __restrict__ counts,
                                              float* __restrict__ loss) {
  int t = threadIdx.x;
  for (int i = t; i < GG*VV; i += 256) counts[i] = 0u;
  if (t == 0) *loss = 0.0f;
}

// Conv GEMM: h[b,g,t,o] = sum_i x[b,t,g*D+i] * conv_w[g*D+o, i]
// 64x64 output tile, BK=16, 4x4 microtile per thread. Also emits per-block
// double (sum, sumsq) partials for deterministic GroupNorm stats.
__global__ __launch_bounds__(256) void k_conv(const float* __restrict__ x,
                                              const float* __restrict__ w,
                                              float* __restrict__ h,
                                              double* __restrict__ part) {
  __shared__ float Xs[16][68];   // [k][t], pad 68 -> conflict-free + 16B-aligned rows
  __shared__ float Ws[16][68];   // [k][o]
  __shared__ double r1[4], r2[4];
  const int bid = blockIdx.x;
  const int bg  = bid >> 7;          // b*G+g
  const int rem = bid & 127;
  const int t0  = (rem >> 2) << 6;
  const int o0  = (rem & 3) << 6;
  const int b = bg >> 1, g = bg & 1;
  const int tid = threadIdx.x;
  const int tx = tid & 15, ty = tid >> 4;   // o-, t- microtile coords
  const int lk = tid & 15, lr = tid >> 4;   // load coords
  const float* xb = x + (size_t)(b*TT + t0)*CC + g*DD;
  const float* wb = w + (size_t)(g*DD + o0)*DD;
  float acc[4][4];
  #pragma unroll
  for (int i = 0; i < 4; i++)
    #pragma unroll
    for (int j = 0; j < 4; j++) acc[i][j] = 0.0f;

  for (int k0 = 0; k0 < DD; k0 += 16) {
    #pragma unroll
    for (int i = 0; i < 4; i++) {
      int row = lr + (i << 4);
      Xs[lk][row] = xb[(size_t)row*CC + k0 + lk];
      Ws[lk][row] = wb[(size_t)row*DD + k0 + lk];
    }
    __syncthreads();
    #pragma unroll
    for (int kk = 0; kk < 16; kk++) {
      const float4 a  = *reinterpret_cast<const float4*>(&Xs[kk][ty << 2]);
      const float4 b4 = *reinterpret_cast<const float4*>(&Ws[kk][tx << 2]);
      float av[4] = {a.x, a.y, a.z, a.w};
      float bv[4] = {b4.x, b4.y, b4.z, b4.w};
      #pragma unroll
      for (int i = 0; i < 4; i++)
        #pragma unroll
        for (int j = 0; j < 4; j++)
          acc[i][j] = fmaf(av[i], bv[j], acc[i][j]);
    }
    __syncthreads();
  }

  float* hb = h + ((size_t)bg*TT + t0)*DD + o0;
  double s1 = 0.0, s2 = 0.0;
  #pragma unroll
  for (int i = 0; i < 4; i++) {
    float4 o;
    o.x = acc[i][0]; o.y = acc[i][1]; o.z = acc[i][2]; o.w = acc[i][3];
    *reinterpret_cast<float4*>(&hb[(size_t)(ty*4 + i)*DD + (tx << 2)]) = o;
    #pragma unroll
    for (int j = 0; j < 4; j++) { double v = (double)acc[i][j]; s1 += v; s2 += v*v; }
  }
  #pragma unroll
  for (int m = 32; m > 0; m >>= 1) { s1 += __shfl_down(s1, m); s2 += __shfl_down(s2, m); }
  const int wv = tid >> 6, ln = tid & 63;
  if (ln == 0) { r1[wv] = s1; r2[wv] = s2; }
  __syncthreads();
  if (tid == 0) {
    part[(size_t)bid*2]     = r1[0] + r1[1] + r1[2] + r1[3];
    part[(size_t)bid*2 + 1] = r2[0] + r2[1] + r2[2] + r2[3];
  }
}

// Finalize mu / rsig per (b,g) — deterministic fixed-order double sum.
__global__ void k_stats(const double* __restrict__ part, float* __restrict__ musig) {
  int i = threadIdx.x;
  if (i < BB*GG) {
    double s1 = 0.0, s2 = 0.0;
    for (int r = 0; r < 128; r++) { s1 += part[(i*128 + r)*2]; s2 += part[(i*128 + r)*2 + 1]; }
    double mu  = s1 / (double)DT;
    double var = s2 / (double)DT - mu*mu;
    double rs  = 1.0 / sqrt(var + 1e-5);
    musig[i*2]     = (float)mu;
    musig[i*2 + 1] = (float)rs;
  }
}

// Transpose embedding -> embT[g][d][v] (coalesced scoring loads) + e_sq in double.
__global__ __launch_bounds__(256) void k_emb(const float* __restrict__ emb,
                                             float* __restrict__ embT,
                                             float* __restrict__ esq) {
  int blk = blockIdx.x;          // 0..39
  int g = blk / 20;
  int v0 = (blk % 20) * 16;
  int tid = threadIdx.x;
  int vl = tid >> 4, dl = tid & 15;
  int v = v0 + vl;
  double sq = 0.0;
  #pragma unroll
  for (int k = 0; k < 16; k++) {
    int d = dl + (k << 4);
    float e = emb[((size_t)v*GG + g)*DD + d];
    embT[((size_t)(g*DD + d))*VV + v] = e;
    sq += (double)e * (double)e;
  }
  #pragma unroll
  for (int m = 1; m < 16; m <<= 1) sq += __shfl_xor(sq, m);
  if (dl == 0) esq[g*VV + v] = (float)sq;
}

// Normalize 16 t-rows, score vs all V codes, argmin (tie->lowest v),
// histogram, write x_out = selected embedding, accumulate loss.
__global__ __launch_bounds__(256) void k_vq(const float* __restrict__ h,
                                            const float* __restrict__ musig,
                                            const float* __restrict__ gn_w,
                                            const float* __restrict__ gn_b,
                                            const float* __restrict__ embT,
                                            const float* __restrict__ esq,
                                            const float* __restrict__ emb,
                                            float* __restrict__ out,
                                            unsigned* __restrict__ counts,
                                            float* __restrict__ loss) {
  __shared__ float  zs[16][260];   // ze rows (pad 260: 16B-aligned rows)
  __shared__ double zsq[16][4];
  __shared__ float  ze2r[16];
  __shared__ int    bestv[16];
  __shared__ float  redf[4];
  const int bid = blockIdx.x;
  const int bg  = bid >> 7;
  const int b = bg >> 1, g = bg & 1;
  const int t0 = (bid & 127) << 4;
  const int tid = threadIdx.x;
  const int wv = tid >> 6, ln = tid & 63;
  const float mu = musig[bg*2], rs = musig[bg*2 + 1];
  const float gw = gn_w[g*DD + tid], gb = gn_b[g*DD + tid];
  const float* hb = h + ((size_t)bg*TT + t0)*DD + tid;

  // Phase 1: normalize (exact numpy op order) + ||ze||^2 per row in double
  #pragma unroll 4
  for (int r = 0; r < 16; r++) {
    float hv = hb[(size_t)r*DD];
    float z = __fmul_rn(__fsub_rn(hv, mu), rs);
    z = __fadd_rn(__fmul_rn(z, gw), gb);
    zs[r][tid] = z;
    double q = (double)z * (double)z;
    #pragma unroll
    for (int m = 32; m > 0; m >>= 1) q += __shfl_down(q, m);
    if (ln == 0) zsq[r][wv] = q;
  }
  __syncthreads();
  if (tid < 16) ze2r[tid] = (float)(zsq[tid][0] + zsq[tid][1] + zsq[tid][2] + zsq[tid][3]);
  __syncthreads();

  // Phase 2: scoring. thread = (row = tid/16, vl = tid%16), 4 v per thread per sweep.
  const int row = tid >> 4, vl = tid & 15;
  const float4* embT4 = reinterpret_cast<const float4*>(embT + (size_t)g*DD*VV);
  const float ze2 = ze2r[row];
  const float* zrow = zs[row];
  float bs = 3.4e38f; int bv = 0x7fffffff;
  for (int vc = 0; vc < 5; vc++) {
    const int vb = vc*64 + (vl << 2);
    float a0 = 0.f, a1 = 0.f, a2 = 0.f, a3 = 0.f;
    #pragma unroll 8
    for (int d = 0; d < DD; d++) {
      float a = zrow[d];
      float4 e = embT4[(size_t)d*80 + (vb >> 2)];
      a0 = fmaf(a, e.x, a0); a1 = fmaf(a, e.y, a1);
      a2 = fmaf(a, e.z, a2); a3 = fmaf(a, e.w, a3);
    }
    float cs[4] = {a0, a1, a2, a3};
    #pragma unroll
    for (int j = 0; j < 4; j++) {
      int v = vb + j;
      float s = __fadd_rn(__fsub_rn(ze2, __fmul_rn(2.0f, cs[j])), esq[g*VV + v]);
      if (s < bs) { bs = s; bv = v; }   // strict < : first-occurrence semantics
    }
  }
  // reduce across the 16 vl-lanes of this row (tie -> lowest v)
  #pragma unroll
  for (int m = 1; m < 16; m <<= 1) {
    float os = __shfl_xor(bs, m);
    int   ov = __shfl_xor(bv, m);
    if (os < bs || (os == bs && ov < bv)) { bs = os; bv = ov; }
  }
  if (vl == 0) bestv[row] = bv;
  __syncthreads();
  if (tid < 16) atomicAdd(&counts[g*VV + bestv[tid]], 1u);

  // Phase 3: x_out = zq, loss partial
  float lp = 0.0f;
  float* ob = out + (size_t)(b*TT + t0)*CC + g*DD + tid;
  #pragma unroll 2
  for (int r = 0; r < 16; r++) {
    int v = bestv[r];
    float e = emb[((size_t)v*GG + g)*DD + tid];
    float z = zs[r][tid];
    float df = e - z;
    lp = fmaf(df, df, lp);
    ob[(size_t)r*CC] = e;
  }
  #pragma unroll
  for (int m = 32; m > 0; m >>= 1) lp += __shfl_down(lp, m);
  if (ln == 0) redf[wv] = lp;
  __syncthreads();
  if (tid == 0) atomicAdd(loss, redf[0] + redf[1] + redf[2] + redf[3]);
}

__global__ __launch_bounds__(256) void k_final(const unsigned* __restrict__ counts,
                                               const float* __restrict__ loss,
                                               float* __restrict__ out) {
  __shared__ float sd[256];
  int tid = threadIdx.x;
  float perp = 0.0f;
  for (int g = 0; g < GG; g++) {
    float p1 = 0.0f;
    for (int v = tid; v < VV; v += 256) {
      float p = (float)counts[g*VV + v] / 32768.0f;
      p1 += p * logf(p + 1e-7f);
    }
    sd[tid] = p1;
    __syncthreads();
    for (int s = 128; s > 0; s >>= 1) {
      if (tid < s) sd[tid] += sd[tid + s];
      __syncthreads();
    }
    if (tid == 0) perp += expf(-sd[0]);
    __syncthreads();
  }
  if (tid == 0) {
    out[NOUT]     = 1.25f * (*loss) / (float)NOUT;
    out[NOUT + 1] = perp;
  }
}

extern "C" void kernel_launch(void* const* d_in, const int* in_sizes, int n_in,
                              void* d_out, int out_size, void* d_ws, size_t ws_size,
                              hipStream_t stream) {
  const float* x   = (const float*)d_in[0];
  const float* cw  = (const float*)d_in[1];
  const float* gnw = (const float*)d_in[2];
  const float* gnb = (const float*)d_in[3];
  const float* emb = (const float*)d_in[4];
  float* out = (float*)d_out;
  char* ws = (char*)d_ws;
  float*    h      = (float*)(ws + OFF_H);
  double*   part   = (double*)(ws + OFF_PART);
  float*    musig  = (float*)(ws + OFF_MUSIG);
  float*    esq    = (float*)(ws + OFF_ESQ);
  unsigned* counts = (unsigned*)(ws + OFF_CNT);
  float*    loss   = (float*)(ws + OFF_LOSS);
  float*    embT   = (float*)(ws + OFF_EMBT);

  hipLaunchKernelGGL(k_init,  dim3(1),    dim3(256), 0, stream, counts, loss);
  hipLaunchKernelGGL(k_conv,  dim3(4096), dim3(256), 0, stream, x, cw, h, part);
  hipLaunchKernelGGL(k_stats, dim3(1),    dim3(32),  0, stream, part, musig);
  hipLaunchKernelGGL(k_emb,   dim3(40),   dim3(256), 0, stream, emb, embT, esq);
  hipLaunchKernelGGL(k_vq,    dim3(4096), dim3(256), 0, stream,
                     h, musig, gnw, gnb, embT, esq, emb, out, counts, loss);
  hipLaunchKernelGGL(k_final, dim3(1),    dim3(256), 0, stream, counts, loss, out);
}

// Round 2
// 366.734 us; speedup vs baseline: 1.9705x; 1.9705x over previous
//
#include <hip/hip_runtime.h>
#include <math.h>

// Problem constants
#define BB 16
#define TT 2048
#define CC 512
#define GG 2
#define DD 256      // C/G
#define VV 320
#define DT (DD*TT)             // 524288 elements per (b,g) group-norm slab
#define NOUT ((size_t)BB*TT*CC) // 16777216

// Workspace layout (bytes)
#define OFF_H      0ULL
#define SZ_H       ((size_t)BB*GG*TT*DD*4)          // 67108864
#define OFF_PART   (OFF_H + SZ_H)                    // 4096 blocks * 2 doubles = 65536
#define OFF_MUSIG  (OFF_PART + 4096ULL*2*8)          // 32 * 2 floats
#define OFF_ESQ    (OFF_MUSIG + 32ULL*2*4)           // G*V floats
#define OFF_CNT    (OFF_ESQ + (size_t)GG*VV*4)       // G*V u32
#define OFF_LOSS   (OFF_CNT + (size_t)GG*VV*4)       // 1 float
#define OFF_EMBT   67180032ULL                        // 256-aligned; G*D*V floats = 655360

__global__ __launch_bounds__(256) void k_init(unsigned* __restrict__ counts,
                                              float* __restrict__ loss) {
  int t = threadIdx.x;
  for (int i = t; i < GG*VV; i += 256) counts[i] = 0u;
  if (t == 0) *loss = 0.0f;
}

// Conv GEMM: h[b,g,t,o] = sum_i x[b,t,g*D+i] * conv_w[g*D+o, i]
__global__ __launch_bounds__(256) void k_conv(const float* __restrict__ x,
                                              const float* __restrict__ w,
                                              float* __restrict__ h,
                                              double* __restrict__ part) {
  __shared__ float Xs[16][68];
  __shared__ float Ws[16][68];
  __shared__ double r1[4], r2[4];
  const int bid = blockIdx.x;
  const int bg  = bid >> 7;          // b*G+g
  const int rem = bid & 127;
  const int t0  = (rem >> 2) << 6;
  const int o0  = (rem & 3) << 6;
  const int b = bg >> 1, g = bg & 1;
  const int tid = threadIdx.x;
  const int tx = tid & 15, ty = tid >> 4;
  const int lk = tid & 15, lr = tid >> 4;
  const float* xb = x + (size_t)(b*TT + t0)*CC + g*DD;
  const float* wb = w + (size_t)(g*DD + o0)*DD;
  float acc[4][4];
  #pragma unroll
  for (int i = 0; i < 4; i++)
    #pragma unroll
    for (int j = 0; j < 4; j++) acc[i][j] = 0.0f;

  for (int k0 = 0; k0 < DD; k0 += 16) {
    #pragma unroll
    for (int i = 0; i < 4; i++) {
      int row = lr + (i << 4);
      Xs[lk][row] = xb[(size_t)row*CC + k0 + lk];
      Ws[lk][row] = wb[(size_t)row*DD + k0 + lk];
    }
    __syncthreads();
    #pragma unroll
    for (int kk = 0; kk < 16; kk++) {
      const float4 a  = *reinterpret_cast<const float4*>(&Xs[kk][ty << 2]);
      const float4 b4 = *reinterpret_cast<const float4*>(&Ws[kk][tx << 2]);
      float av[4] = {a.x, a.y, a.z, a.w};
      float bv[4] = {b4.x, b4.y, b4.z, b4.w};
      #pragma unroll
      for (int i = 0; i < 4; i++)
        #pragma unroll
        for (int j = 0; j < 4; j++)
          acc[i][j] = fmaf(av[i], bv[j], acc[i][j]);
    }
    __syncthreads();
  }

  float* hb = h + ((size_t)bg*TT + t0)*DD + o0;
  double s1 = 0.0, s2 = 0.0;
  #pragma unroll
  for (int i = 0; i < 4; i++) {
    float4 o;
    o.x = acc[i][0]; o.y = acc[i][1]; o.z = acc[i][2]; o.w = acc[i][3];
    *reinterpret_cast<float4*>(&hb[(size_t)(ty*4 + i)*DD + (tx << 2)]) = o;
    #pragma unroll
    for (int j = 0; j < 4; j++) { double v = (double)acc[i][j]; s1 += v; s2 += v*v; }
  }
  #pragma unroll
  for (int m = 32; m > 0; m >>= 1) { s1 += __shfl_down(s1, m); s2 += __shfl_down(s2, m); }
  const int wv = tid >> 6, ln = tid & 63;
  if (ln == 0) { r1[wv] = s1; r2[wv] = s2; }
  __syncthreads();
  if (tid == 0) {
    part[(size_t)bid*2]     = r1[0] + r1[1] + r1[2] + r1[3];
    part[(size_t)bid*2 + 1] = r2[0] + r2[1] + r2[2] + r2[3];
  }
}

__global__ void k_stats(const double* __restrict__ part, float* __restrict__ musig) {
  int i = threadIdx.x;
  if (i < BB*GG) {
    double s1 = 0.0, s2 = 0.0;
    for (int r = 0; r < 128; r++) { s1 += part[(i*128 + r)*2]; s2 += part[(i*128 + r)*2 + 1]; }
    double mu  = s1 / (double)DT;
    double var = s2 / (double)DT - mu*mu;
    double rs  = 1.0 / sqrt(var + 1e-5);
    musig[i*2]     = (float)mu;
    musig[i*2 + 1] = (float)rs;
  }
}

__global__ __launch_bounds__(256) void k_emb(const float* __restrict__ emb,
                                             float* __restrict__ embT,
                                             float* __restrict__ esq) {
  int blk = blockIdx.x;          // 0..39
  int g = blk / 20;
  int v0 = (blk % 20) * 16;
  int tid = threadIdx.x;
  int vl = tid >> 4, dl = tid & 15;
  int v = v0 + vl;
  double sq = 0.0;
  #pragma unroll
  for (int k = 0; k < 16; k++) {
    int d = dl + (k << 4);
    float e = emb[((size_t)v*GG + g)*DD + d];
    embT[((size_t)(g*DD + d))*VV + v] = e;
    sq += (double)e * (double)e;
  }
  #pragma unroll
  for (int m = 1; m < 16; m <<= 1) sq += __shfl_xor(sq, m);
  if (dl == 0) esq[g*VV + v] = (float)sq;
}

// VQ scoring as a tiled GEMM: block = 64 t-rows x 320 v, BK=32,
// 4t x 20v register microtile per thread. Exact fp32 op order preserved
// (sequential fmaf over d=0..255 per (t,v); same s-formula; same argmin order).
__global__ __launch_bounds__(256) void k_vq(const float* __restrict__ h,
                                            const float* __restrict__ musig,
                                            const float* __restrict__ gn_w,
                                            const float* __restrict__ gn_b,
                                            const float* __restrict__ embT,
                                            const float* __restrict__ esq,
                                            const float* __restrict__ emb,
                                            float* __restrict__ out,
                                            unsigned* __restrict__ counts,
                                            float* __restrict__ loss) {
  __shared__ float  As[32][64];     // [k][t]  8 KB
  __shared__ float  Bs[32][320];    // [k][v]  40 KB
  __shared__ double zsqs[64][4];    // 2 KB
  __shared__ float  ze2s[64];
  __shared__ int    bestvs[64];
  __shared__ float  redf[4];

  const int bid = blockIdx.x;       // 1024 blocks
  const int bg  = bid >> 5;         // b*G+g
  const int t0  = (bid & 31) << 6;
  const int b = bg >> 1, g = bg & 1;
  const int tid = threadIdx.x;
  const int wv = tid >> 6, ln = tid & 63;
  const int tx = tid & 15, ty = tid >> 4;
  const float mu = musig[bg*2], rs = musig[bg*2 + 1];
  const float* hb = h + ((size_t)bg*TT + t0)*DD;
  const float gw = gn_w[g*DD + tid];
  const float gb = gn_b[g*DD + tid];

  // Phase 1: ||ze||^2 per row, double, exact same reduce order as before.
  #pragma unroll 2
  for (int r = 0; r < 64; ++r) {
    float hv = hb[(size_t)r*DD + tid];
    float z = __fmul_rn(__fsub_rn(hv, mu), rs);
    z = __fadd_rn(__fmul_rn(z, gw), gb);
    double q = (double)z * (double)z;
    #pragma unroll
    for (int m = 32; m > 0; m >>= 1) q += __shfl_down(q, m);
    if (ln == 0) zsqs[r][wv] = q;
  }
  __syncthreads();
  if (tid < 64) ze2s[tid] = (float)(zsqs[tid][0] + zsqs[tid][1] + zsqs[tid][2] + zsqs[tid][3]);

  // Phase 2: GEMM. acc[i][j*4+e] = dot(ze[t0+ty*4+i][:], embT[:][64j+4tx+e])
  float acc[4][20];
  #pragma unroll
  for (int i = 0; i < 4; i++)
    #pragma unroll
    for (int j = 0; j < 20; j++) acc[i][j] = 0.0f;
  const float* wgp = gn_w + g*DD;
  const float* bgp = gn_b + g*DD;
  const float* eT  = embT + (size_t)g*DD*VV;

  for (int k0 = 0; k0 < DD; k0 += 32) {
    __syncthreads();
    // stage A (normalize on the fly): 2 float4 loads / thread
    #pragma unroll
    for (int q = 0; q < 2; ++q) {
      int u = (tid << 1) + q;           // 0..511
      int t = u >> 3, k4 = u & 7;
      float4 hx = *reinterpret_cast<const float4*>(&hb[(size_t)t*DD + k0 + (k4 << 2)]);
      float hv[4] = {hx.x, hx.y, hx.z, hx.w};
      #pragma unroll
      for (int e = 0; e < 4; ++e) {
        int d = k0 + (k4 << 2) + e;
        float z = __fmul_rn(__fsub_rn(hv[e], mu), rs);
        z = __fadd_rn(__fmul_rn(z, wgp[d]), bgp[d]);
        As[(k4 << 2) + e][t] = z;
      }
    }
    // stage B: 10 float4 loads / thread
    #pragma unroll
    for (int j = 0; j < 10; ++j) {
      int u = (j << 8) + tid;           // 0..2559
      int k = u / 80, v4 = u - k*80;
      *reinterpret_cast<float4*>(&Bs[k][v4 << 2]) =
          *reinterpret_cast<const float4*>(&eT[(size_t)(k0 + k)*VV + (v4 << 2)]);
    }
    __syncthreads();
    #pragma unroll 4
    for (int kk = 0; kk < 32; ++kk) {
      const float4 a = *reinterpret_cast<const float4*>(&As[kk][ty << 2]);
      float av[4] = {a.x, a.y, a.z, a.w};
      #pragma unroll
      for (int j = 0; j < 5; ++j) {
        const float4 b4 = *reinterpret_cast<const float4*>(&Bs[kk][(j << 6) + (tx << 2)]);
        float bv[4] = {b4.x, b4.y, b4.z, b4.w};
        #pragma unroll
        for (int i = 0; i < 4; ++i)
          #pragma unroll
          for (int e = 0; e < 4; ++e)
            acc[i][(j << 2) + e] = fmaf(av[i], bv[e], acc[i][(j << 2) + e]);
      }
    }
  }

  // Epilogue: per-row argmin, ascending v visit order, strict <, tie->lower v.
  const float* esg = esq + g*VV;
  #pragma unroll
  for (int i = 0; i < 4; ++i) {
    const float ze2 = ze2s[(ty << 2) + i];
    float bs = 3.4e38f; int bv = 0x7fffffff;
    #pragma unroll
    for (int j = 0; j < 5; ++j)
      #pragma unroll
      for (int e = 0; e < 4; ++e) {
        int v = (j << 6) + (tx << 2) + e;
        float s = __fadd_rn(__fsub_rn(ze2, __fmul_rn(2.0f, acc[i][(j << 2) + e])), esg[v]);
        if (s < bs) { bs = s; bv = v; }
      }
    #pragma unroll
    for (int m = 1; m < 16; m <<= 1) {
      float os = __shfl_xor(bs, m);
      int   ov = __shfl_xor(bv, m);
      if (os < bs || (os == bs && ov < bv)) { bs = os; bv = ov; }
    }
    if (tx == 0) bestvs[(ty << 2) + i] = bv;
  }
  __syncthreads();
  if (tid < 64) atomicAdd(&counts[g*VV + bestvs[tid]], 1u);

  // Phase 3: x_out = selected embedding; loss partial (recompute z from h).
  float lp = 0.0f;
  float* ob = out + (size_t)(b*TT + t0)*CC + g*DD + tid;
  #pragma unroll 2
  for (int r = 0; r < 64; ++r) {
    int v = bestvs[r];
    float e = emb[((size_t)v*GG + g)*DD + tid];
    float hv = hb[(size_t)r*DD + tid];
    float z = __fmul_rn(__fsub_rn(hv, mu), rs);
    z = __fadd_rn(__fmul_rn(z, gw), gb);
    float df = e - z;
    lp = fmaf(df, df, lp);
    ob[(size_t)r*CC] = e;
  }
  #pragma unroll
  for (int m = 32; m > 0; m >>= 1) lp += __shfl_down(lp, m);
  if (ln == 0) redf[wv] = lp;
  __syncthreads();
  if (tid == 0) atomicAdd(loss, redf[0] + redf[1] + redf[2] + redf[3]);
}

__global__ __launch_bounds__(256) void k_final(const unsigned* __restrict__ counts,
                                               const float* __restrict__ loss,
                                               float* __restrict__ out) {
  __shared__ float sd[256];
  int tid = threadIdx.x;
  float perp = 0.0f;
  for (int g = 0; g < GG; g++) {
    float p1 = 0.0f;
    for (int v = tid; v < VV; v += 256) {
      float p = (float)counts[g*VV + v] / 32768.0f;
      p1 += p * logf(p + 1e-7f);
    }
    sd[tid] = p1;
    __syncthreads();
    for (int s = 128; s > 0; s >>= 1) {
      if (tid < s) sd[tid] += sd[tid + s];
      __syncthreads();
    }
    if (tid == 0) perp += expf(-sd[0]);
    __syncthreads();
  }
  if (tid == 0) {
    out[NOUT]     = 1.25f * (*loss) / (float)NOUT;
    out[NOUT + 1] = perp;
  }
}

extern "C" void kernel_launch(void* const* d_in, const int* in_sizes, int n_in,
                              void* d_out, int out_size, void* d_ws, size_t ws_size,
                              hipStream_t stream) {
  const float* x   = (const float*)d_in[0];
  const float* cw  = (const float*)d_in[1];
  const float* gnw = (const float*)d_in[2];
  const float* gnb = (const float*)d_in[3];
  const float* emb = (const float*)d_in[4];
  float* out = (float*)d_out;
  char* ws = (char*)d_ws;
  float*    h      = (float*)(ws + OFF_H);
  double*   part   = (double*)(ws + OFF_PART);
  float*    musig  = (float*)(ws + OFF_MUSIG);
  float*    esq    = (float*)(ws + OFF_ESQ);
  unsigned* counts = (unsigned*)(ws + OFF_CNT);
  float*    loss   = (float*)(ws + OFF_LOSS);
  float*    embT   = (float*)(ws + OFF_EMBT);

  hipLaunchKernelGGL(k_init,  dim3(1),    dim3(256), 0, stream, counts, loss);
  hipLaunchKernelGGL(k_conv,  dim3(4096), dim3(256), 0, stream, x, cw, h, part);
  hipLaunchKernelGGL(k_stats, dim3(1),    dim3(32),  0, stream, part, musig);
  hipLaunchKernelGGL(k_emb,   dim3(40),   dim3(256), 0, stream, emb, embT, esq);
  hipLaunchKernelGGL(k_vq,    dim3(1024), dim3(256), 0, stream,
                     h, musig, gnw, gnb, embT, esq, emb, out, counts, loss);
  hipLaunchKernelGGL(k_final, dim3(1),    dim3(256), 0, stream, counts, loss, out);
}

// Round 3
// 232.506 us; speedup vs baseline: 3.1081x; 1.5773x over previous
//
#include <hip/hip_runtime.h>
#include <math.h>

// Problem constants
#define BB 16
#define TT 2048
#define CC 512
#define GG 2
#define DD 256      // C/G
#define VV 320
#define DT (DD*TT)
#define NOUT ((size_t)BB*TT*CC)

// Workspace layout (bytes) — total 67,835,392 (same footprint as round 2)
#define OFF_H      0ULL
#define SZ_H       ((size_t)BB*GG*TT*DD*4)          // 67108864
#define OFF_PART   (OFF_H + SZ_H)
#define OFF_MUSIG  (OFF_PART + 4096ULL*2*8)
#define OFF_ESQ    (OFF_MUSIG + 32ULL*2*4)
#define OFF_CNT    (OFF_ESQ + (size_t)GG*VV*4)
#define OFF_LOSS   (OFF_CNT + (size_t)GG*VV*4)
#define OFF_EMBH   67180032ULL                       // fp16-hi plane: G*8*4*320*8 halfs = 327680 B
#define OFF_EMBL   (OFF_EMBH + 327680ULL)            // fp16-lo plane: 327680 B

typedef _Float16 half8   __attribute__((ext_vector_type(8)));
typedef _Float16 half4_t __attribute__((ext_vector_type(4)));
typedef float    f32x4   __attribute__((ext_vector_type(4)));

#define MARGIN 5e-4f

__global__ __launch_bounds__(256) void k_init(unsigned* __restrict__ counts,
                                              float* __restrict__ loss) {
  int t = threadIdx.x;
  for (int i = t; i < GG*VV; i += 256) counts[i] = 0u;
  if (t == 0) *loss = 0.0f;
}

// Conv GEMM (unchanged, exact fp32): h[b,g,t,o] = sum_i x[b,t,g*D+i]*w[g*D+o,i]
__global__ __launch_bounds__(256) void k_conv(const float* __restrict__ x,
                                              const float* __restrict__ w,
                                              float* __restrict__ h,
                                              double* __restrict__ part) {
  __shared__ float Xs[16][68];
  __shared__ float Ws[16][68];
  __shared__ double r1[4], r2[4];
  const int bid = blockIdx.x;
  const int bg  = bid >> 7;
  const int rem = bid & 127;
  const int t0  = (rem >> 2) << 6;
  const int o0  = (rem & 3) << 6;
  const int b = bg >> 1, g = bg & 1;
  const int tid = threadIdx.x;
  const int tx = tid & 15, ty = tid >> 4;
  const int lk = tid & 15, lr = tid >> 4;
  const float* xb = x + (size_t)(b*TT + t0)*CC + g*DD;
  const float* wb = w + (size_t)(g*DD + o0)*DD;
  float acc[4][4];
  #pragma unroll
  for (int i = 0; i < 4; i++)
    #pragma unroll
    for (int j = 0; j < 4; j++) acc[i][j] = 0.0f;

  for (int k0 = 0; k0 < DD; k0 += 16) {
    #pragma unroll
    for (int i = 0; i < 4; i++) {
      int row = lr + (i << 4);
      Xs[lk][row] = xb[(size_t)row*CC + k0 + lk];
      Ws[lk][row] = wb[(size_t)row*DD + k0 + lk];
    }
    __syncthreads();
    #pragma unroll
    for (int kk = 0; kk < 16; kk++) {
      const float4 a  = *reinterpret_cast<const float4*>(&Xs[kk][ty << 2]);
      const float4 b4 = *reinterpret_cast<const float4*>(&Ws[kk][tx << 2]);
      float av[4] = {a.x, a.y, a.z, a.w};
      float bv[4] = {b4.x, b4.y, b4.z, b4.w};
      #pragma unroll
      for (int i = 0; i < 4; i++)
        #pragma unroll
        for (int j = 0; j < 4; j++)
          acc[i][j] = fmaf(av[i], bv[j], acc[i][j]);
    }
    __syncthreads();
  }

  float* hb = h + ((size_t)bg*TT + t0)*DD + o0;
  double s1 = 0.0, s2 = 0.0;
  #pragma unroll
  for (int i = 0; i < 4; i++) {
    float4 o;
    o.x = acc[i][0]; o.y = acc[i][1]; o.z = acc[i][2]; o.w = acc[i][3];
    *reinterpret_cast<float4*>(&hb[(size_t)(ty*4 + i)*DD + (tx << 2)]) = o;
    #pragma unroll
    for (int j = 0; j < 4; j++) { double v = (double)acc[i][j]; s1 += v; s2 += v*v; }
  }
  #pragma unroll
  for (int m = 32; m > 0; m >>= 1) { s1 += __shfl_down(s1, m); s2 += __shfl_down(s2, m); }
  const int wv = tid >> 6, ln = tid & 63;
  if (ln == 0) { r1[wv] = s1; r2[wv] = s2; }
  __syncthreads();
  if (tid == 0) {
    part[(size_t)bid*2]     = r1[0] + r1[1] + r1[2] + r1[3];
    part[(size_t)bid*2 + 1] = r2[0] + r2[1] + r2[2] + r2[3];
  }
}

__global__ void k_stats(const double* __restrict__ part, float* __restrict__ musig) {
  int i = threadIdx.x;
  if (i < BB*GG) {
    double s1 = 0.0, s2 = 0.0;
    for (int r = 0; r < 128; r++) { s1 += part[(i*128 + r)*2]; s2 += part[(i*128 + r)*2 + 1]; }
    double mu  = s1 / (double)DT;
    double var = s2 / (double)DT - mu*mu;
    double rs  = 1.0 / sqrt(var + 1e-5);
    musig[i*2]     = (float)mu;
    musig[i*2 + 1] = (float)rs;
  }
}

// esq (bit-identical to round 2) + fp16 hi/lo planes in MFMA chunk layout:
// plane[g][c][hgrp][v][j], k = c*32 + hgrp*4 + (j&3) + 16*(j>>2)
__global__ __launch_bounds__(256) void k_emb(const float* __restrict__ emb,
                                             _Float16* __restrict__ embHp,
                                             _Float16* __restrict__ embLp,
                                             float* __restrict__ esq) {
  int blk = blockIdx.x;          // 0..39
  int g = blk / 20;
  int v0 = (blk % 20) * 16;
  int tid = threadIdx.x;
  int vl = tid >> 4, dl = tid & 15;
  int v = v0 + vl;
  double sq = 0.0;
  #pragma unroll
  for (int k = 0; k < 16; k++) {
    int d = dl + (k << 4);
    float e = emb[((size_t)v*GG + g)*DD + d];
    sq += (double)e * (double)e;
  }
  #pragma unroll
  for (int m = 1; m < 16; m <<= 1) sq += __shfl_xor(sq, m);
  if (dl == 0) esq[g*VV + v] = (float)sq;

  // fp16 planes
  const int hgrp = dl >> 2, jb = dl & 3;
  #pragma unroll
  for (int c = 0; c < 8; ++c) {
    int k0 = (c << 5) + (hgrp << 2) + jb;   // j = jb
    int k1 = k0 + 16;                        // j = jb+4
    float e0 = emb[((size_t)v*GG + g)*DD + k0];
    float e1 = emb[((size_t)v*GG + g)*DD + k1];
    size_t base = (((size_t)(g*8 + c)*4 + hgrp)*320 + v)*8;
    _Float16 h0 = (_Float16)e0, h1 = (_Float16)e1;
    embHp[base + jb]     = h0;
    embHp[base + jb + 4] = h1;
    embLp[base + jb]     = (_Float16)(e0 - (float)h0);
    embLp[base + jb + 4] = (_Float16)(e1 - (float)h1);
  }
}

// MFMA-based VQ: 128 t-rows x 320 v per block, fp16-split 3-pass, exact recheck.
__global__ __launch_bounds__(256, 2) void k_vq2(const float* __restrict__ h,
                                                const float* __restrict__ musig,
                                                const float* __restrict__ gn_w,
                                                const float* __restrict__ gn_b,
                                                const _Float16* __restrict__ embH,
                                                const _Float16* __restrict__ embL,
                                                const float* __restrict__ esq,
                                                const float* __restrict__ emb,
                                                float* __restrict__ out,
                                                unsigned* __restrict__ counts,
                                                float* __restrict__ loss) {
  __shared__ __align__(16) char smem[59392];
  _Float16* BsH = (_Float16*)smem;               // [4][320][8] halfs, 20480 B
  _Float16* BsL = (_Float16*)(smem + 20480);
  _Float16* AsH = (_Float16*)(smem + 40960);     // [4][128][8] halfs, 8192 B
  _Float16* AsL = (_Float16*)(smem + 49152);
  float* gnws = (float*)(smem + 57344);          // 256 f
  float* gnbs = (float*)(smem + 58368);          // 256 f
  // epilogue overlay (aliases Bs region, used only after K-loop):
  float*  esqs    = (float*)smem;                // 320 f
  int*    candcnt = (int*)(smem + 1280);         // 128
  int*    bestv   = (int*)(smem + 1792);         // 128
  int*    slowl   = (int*)(smem + 2304);         // 128
  int*    nslow   = (int*)(smem + 2816);
  double* zsqs    = (double*)(smem + 2824);      // 4
  float*  scratch = (float*)(smem + 2864);       // 256 f
  unsigned short* cand = (unsigned short*)(smem + 3888);  // [128][24]
  float*  candd2  = (float*)(smem + 10032);      // 24

  const int bid = blockIdx.x;        // 512 blocks
  const int bg  = bid >> 4;
  const int t0  = (bid & 15) << 7;
  const int b = bg >> 1, g = bg & 1;
  const int tid = threadIdx.x;
  const int lane = tid & 63, wv = tid >> 6;
  const int l15 = tid & 15, lh = lane >> 4;
  const float mu = musig[bg*2], rs = musig[bg*2 + 1];
  const float* hb = h + ((size_t)bg*TT + t0)*DD;

  gnws[tid] = gn_w[g*DD + tid];
  gnbs[tid] = gn_b[g*DD + tid];

  f32x4 acc[2][20];
  #pragma unroll
  for (int tf = 0; tf < 2; ++tf)
    #pragma unroll
    for (int vf = 0; vf < 20; ++vf) acc[tf][vf] = 0.0f;

  const int ast_t  = tid >> 1;          // 0..127
  const int ast_kh = (tid & 1) << 4;    // 0 / 16
  const int ast_jb = ast_kh ? 4 : 0;
  const _Float16* gBH = embH + (size_t)(g*8)*10240;
  const _Float16* gBL = embL + (size_t)(g*8)*10240;

  for (int c = 0; c < 8; ++c) {
    __syncthreads();
    // stage B (straight copy, layout prebuilt in k_emb)
    {
      const uint4* sH = (const uint4*)(gBH + (size_t)c*10240);
      const uint4* sL = (const uint4*)(gBL + (size_t)c*10240);
      uint4* dH = (uint4*)BsH; uint4* dL = (uint4*)BsL;
      #pragma unroll
      for (int i = 0; i < 5; ++i) {
        dH[tid + (i << 8)] = sH[tid + (i << 8)];
        dL[tid + (i << 8)] = sL[tid + (i << 8)];
      }
    }
    // stage A: load h, normalize (exact op order), fp16-split, pack
    {
      const int k0 = c << 5;
      const float* src = hb + (size_t)ast_t*DD + k0 + ast_kh;
      #pragma unroll
      for (int q = 0; q < 4; ++q) {
        float4 hx = *(const float4*)(src + (q << 2));
        float hv[4] = {hx.x, hx.y, hx.z, hx.w};
        half4_t vh, vl;
        #pragma unroll
        for (int e = 0; e < 4; ++e) {
          int dd = ast_kh + (q << 2) + e;
          float z = __fmul_rn(__fsub_rn(hv[e], mu), rs);
          z = __fadd_rn(__fmul_rn(z, gnws[k0 + dd]), gnbs[k0 + dd]);
          _Float16 zh = (_Float16)z;
          vh[e] = zh;
          vl[e] = (_Float16)(z - (float)zh);
        }
        *(half4_t*)(AsH + (((q << 7) + ast_t) << 3) + ast_jb) = vh;
        *(half4_t*)(AsL + (((q << 7) + ast_t) << 3) + ast_jb) = vl;
      }
    }
    __syncthreads();
    // MFMA: wave covers rows [wv*32, wv*32+32), all 320 v
    {
      half8 ah[2], al[2];
      #pragma unroll
      for (int tf = 0; tf < 2; ++tf) {
        int t = (wv << 5) + (tf << 4) + l15;
        ah[tf] = *(const half8*)(AsH + (((lh << 7) + t) << 3));
        al[tf] = *(const half8*)(AsL + (((lh << 7) + t) << 3));
      }
      #pragma unroll
      for (int vf = 0; vf < 20; ++vf) {
        int v = (vf << 4) + l15;
        half8 bh = *(const half8*)(BsH + ((lh*320 + v) << 3));
        half8 bl = *(const half8*)(BsL + ((lh*320 + v) << 3));
        #pragma unroll
        for (int tf = 0; tf < 2; ++tf) {
          acc[tf][vf] = __builtin_amdgcn_mfma_f32_16x16x32_f16(ah[tf], bh, acc[tf][vf], 0, 0, 0);
          acc[tf][vf] = __builtin_amdgcn_mfma_f32_16x16x32_f16(al[tf], bh, acc[tf][vf], 0, 0, 0);
          acc[tf][vf] = __builtin_amdgcn_mfma_f32_16x16x32_f16(ah[tf], bl, acc[tf][vf], 0, 0, 0);
        }
      }
    }
  }
  __syncthreads();

  // ---- epilogue: overlay init ----
  if (tid < 160) { esqs[tid] = esq[g*VV + tid]; esqs[tid + 160] = esq[g*VV + tid + 160]; }
  if (tid < 128) { candcnt[tid] = 0; bestv[tid] = -1; }
  if (tid == 0) *nslow = 0;
  __syncthreads();

  // selection: y = esq - 2c'; candidates within MARGIN of row min
  #pragma unroll
  for (int tf = 0; tf < 2; ++tf) {
    #pragma unroll
    for (int reg = 0; reg < 4; ++reg) {
      int row = (wv << 5) + (tf << 4) + (lh << 2) + reg;
      float y[20]; float mn = 3.4e38f;
      #pragma unroll
      for (int vf = 0; vf < 20; ++vf) {
        y[vf] = fmaf(-2.0f, acc[tf][vf][reg], esqs[(vf << 4) + l15]);
        mn = fminf(mn, y[vf]);
      }
      #pragma unroll
      for (int m = 1; m < 16; m <<= 1) mn = fminf(mn, __shfl_xor(mn, m));
      float thr = mn + MARGIN;
      #pragma unroll
      for (int vf = 0; vf < 20; ++vf) {
        if (y[vf] <= thr) {
          int pos = atomicAdd(&candcnt[row], 1);
          if (pos < 24) cand[row*24 + pos] = (unsigned short)((vf << 4) + l15);
        }
      }
    }
  }
  __syncthreads();
  if (tid < 128) {
    int cnt = candcnt[tid];
    if (cnt == 1) bestv[tid] = cand[tid*24];
    else { int p = atomicAdd(nslow, 1); slowl[p] = tid; }
  }
  __syncthreads();

  // slow path: exact re-score (bit-identical to round-2 arithmetic)
  const int ns = *nslow;
  for (int i = 0; i < ns; ++i) {
    const int row = slowl[i];
    float hv = hb[(size_t)row*DD + tid];
    float z = __fmul_rn(__fsub_rn(hv, mu), rs);
    z = __fadd_rn(__fmul_rn(z, gnws[tid]), gnbs[tid]);
    scratch[tid] = z;
    double q = (double)z * (double)z;
    #pragma unroll
    for (int m = 32; m > 0; m >>= 1) q += __shfl_down(q, m);
    if (lane == 0) zsqs[wv] = q;
    __syncthreads();
    const float ze2f = (float)(zsqs[0] + zsqs[1] + zsqs[2] + zsqs[3]);
    const int cnt = candcnt[row];
    if (cnt <= 24) {
      if (tid < cnt) {
        int v = cand[row*24 + tid];
        float cc = 0.0f;
        const float* ep = emb + ((size_t)v*GG + g)*DD;
        for (int d = 0; d < DD; ++d) cc = fmaf(scratch[d], ep[d], cc);
        candd2[tid] = __fadd_rn(__fsub_rn(ze2f, __fmul_rn(2.0f, cc)), esqs[v]);
      }
      __syncthreads();
      if (tid == 0) {
        float bd = 3.4e38f; int bv = 0x7fffffff;
        for (int ci = 0; ci < cnt; ++ci) {
          int v = cand[row*24 + ci]; float d2 = candd2[ci];
          if (d2 < bd || (d2 == bd && v < bv)) { bd = d2; bv = v; }
        }
        bestv[row] = bv;
      }
    } else {
      if (tid == 0) {  // overflow fallback (effectively unreachable)
        float bd = 3.4e38f; int bv = 0x7fffffff;
        for (int v = 0; v < VV; ++v) {
          float cc = 0.0f;
          const float* ep = emb + ((size_t)v*GG + g)*DD;
          for (int d = 0; d < DD; ++d) cc = fmaf(scratch[d], ep[d], cc);
          float d2 = __fadd_rn(__fsub_rn(ze2f, __fmul_rn(2.0f, cc)), esqs[v]);
          if (d2 < bd) { bd = d2; bv = v; }
        }
        bestv[row] = bv;
      }
    }
    __syncthreads();
  }

  if (tid < 128) atomicAdd(&counts[g*VV + bestv[tid]], 1u);

  // x_out = selected embedding; loss partial
  float lp = 0.0f;
  float* ob = out + (size_t)(b*TT + t0)*CC + g*DD + tid;
  const float gw = gnws[tid], gb2 = gnbs[tid];
  for (int r = 0; r < 128; ++r) {
    int v = bestv[r];
    float e = emb[((size_t)v*GG + g)*DD + tid];
    float hv = hb[(size_t)r*DD + tid];
    float z = __fmul_rn(__fsub_rn(hv, mu), rs);
    z = __fadd_rn(__fmul_rn(z, gw), gb2);
    float df = e - z;
    lp = fmaf(df, df, lp);
    ob[(size_t)r*CC] = e;
  }
  #pragma unroll
  for (int m = 32; m > 0; m >>= 1) lp += __shfl_down(lp, m);
  if (lane == 0) scratch[wv] = lp;
  __syncthreads();
  if (tid == 0) atomicAdd(loss, scratch[0] + scratch[1] + scratch[2] + scratch[3]);
}

__global__ __launch_bounds__(256) void k_final(const unsigned* __restrict__ counts,
                                               const float* __restrict__ loss,
                                               float* __restrict__ out) {
  __shared__ float sd[256];
  int tid = threadIdx.x;
  float perp = 0.0f;
  for (int g = 0; g < GG; g++) {
    float p1 = 0.0f;
    for (int v = tid; v < VV; v += 256) {
      float p = (float)counts[g*VV + v] / 32768.0f;
      p1 += p * logf(p + 1e-7f);
    }
    sd[tid] = p1;
    __syncthreads();
    for (int s = 128; s > 0; s >>= 1) {
      if (tid < s) sd[tid] += sd[tid + s];
      __syncthreads();
    }
    if (tid == 0) perp += expf(-sd[0]);
    __syncthreads();
  }
  if (tid == 0) {
    out[NOUT]     = 1.25f * (*loss) / (float)NOUT;
    out[NOUT + 1] = perp;
  }
}

extern "C" void kernel_launch(void* const* d_in, const int* in_sizes, int n_in,
                              void* d_out, int out_size, void* d_ws, size_t ws_size,
                              hipStream_t stream) {
  const float* x   = (const float*)d_in[0];
  const float* cw  = (const float*)d_in[1];
  const float* gnw = (const float*)d_in[2];
  const float* gnb = (const float*)d_in[3];
  const float* emb = (const float*)d_in[4];
  float* out = (float*)d_out;
  char* ws = (char*)d_ws;
  float*     h      = (float*)(ws + OFF_H);
  double*    part   = (double*)(ws + OFF_PART);
  float*     musig  = (float*)(ws + OFF_MUSIG);
  float*     esq    = (float*)(ws + OFF_ESQ);
  unsigned*  counts = (unsigned*)(ws + OFF_CNT);
  float*     loss   = (float*)(ws + OFF_LOSS);
  _Float16*  embH   = (_Float16*)(ws + OFF_EMBH);
  _Float16*  embL   = (_Float16*)(ws + OFF_EMBL);

  hipLaunchKernelGGL(k_init,  dim3(1),    dim3(256), 0, stream, counts, loss);
  hipLaunchKernelGGL(k_conv,  dim3(4096), dim3(256), 0, stream, x, cw, h, part);
  hipLaunchKernelGGL(k_stats, dim3(1),    dim3(32),  0, stream, part, musig);
  hipLaunchKernelGGL(k_emb,   dim3(40),   dim3(256), 0, stream, emb, embH, embL, esq);
  hipLaunchKernelGGL(k_vq2,   dim3(512),  dim3(256), 0, stream,
                     h, musig, gnw, gnb, embH, embL, esq, emb, out, counts, loss);
  hipLaunchKernelGGL(k_final, dim3(1),    dim3(256), 0, stream, counts, loss, out);
}

// Round 4
// 140.103 us; speedup vs baseline: 5.1580x; 1.6595x over previous
//
#include <hip/hip_runtime.h>
#include <math.h>

// Problem constants
#define BB 16
#define TT 2048
#define CC 512
#define GG 2
#define DD 256      // C/G
#define VV 320
#define DT (DD*TT)
#define NOUT ((size_t)BB*TT*CC)

// Workspace layout (bytes) — total 67,835,392 (identical footprint to round 3)
#define OFF_H      0ULL
#define SZ_H       ((size_t)BB*GG*TT*DD*4)          // 67108864
#define OFF_PART   (OFF_H + SZ_H)                    // 512 blocks * 2 doubles
#define OFF_MUSIG  (OFF_PART + 4096ULL*2*8)
#define OFF_ESQ    (OFF_MUSIG + 32ULL*2*4)
#define OFF_CNT    (OFF_ESQ + (size_t)GG*VV*4)
#define OFF_LOSS   (OFF_CNT + (size_t)GG*VV*4)
#define OFF_EMBH   67180032ULL                       // fp16-hi plane: G*8*4*320*8 halfs
#define OFF_EMBL   (OFF_EMBH + 327680ULL)            // fp16-lo plane

typedef _Float16 half8   __attribute__((ext_vector_type(8)));
typedef _Float16 half4_t __attribute__((ext_vector_type(4)));
typedef float    f32x4   __attribute__((ext_vector_type(4)));

#define MARGIN 5e-4f

// esq + fp16 hi/lo emb planes (blocks 0..39) + init counts/loss (block 40).
// plane[g][c][hgrp][v][j], k = c*32 + hgrp*4 + (j&3) + 16*(j>>2)
__global__ __launch_bounds__(256) void k_emb(const float* __restrict__ emb,
                                             _Float16* __restrict__ embHp,
                                             _Float16* __restrict__ embLp,
                                             float* __restrict__ esq,
                                             unsigned* __restrict__ counts,
                                             float* __restrict__ loss) {
  int blk = blockIdx.x;
  int tid = threadIdx.x;
  if (blk == 40) {      // init block
    for (int i = tid; i < GG*VV; i += 256) counts[i] = 0u;
    if (tid == 0) *loss = 0.0f;
    return;
  }
  int g = blk / 20;
  int v0 = (blk % 20) * 16;
  int vl = tid >> 4, dl = tid & 15;
  int v = v0 + vl;
  double sq = 0.0;
  #pragma unroll
  for (int k = 0; k < 16; k++) {
    int d = dl + (k << 4);
    float e = emb[((size_t)v*GG + g)*DD + d];
    sq += (double)e * (double)e;
  }
  #pragma unroll
  for (int m = 1; m < 16; m <<= 1) sq += __shfl_xor(sq, m);
  if (dl == 0) esq[g*VV + v] = (float)sq;

  const int hgrp = dl >> 2, jb = dl & 3;
  #pragma unroll
  for (int c = 0; c < 8; ++c) {
    int k0 = (c << 5) + (hgrp << 2) + jb;
    int k1 = k0 + 16;
    float e0 = emb[((size_t)v*GG + g)*DD + k0];
    float e1 = emb[((size_t)v*GG + g)*DD + k1];
    size_t base = (((size_t)(g*8 + c)*4 + hgrp)*320 + v)*8;
    _Float16 h0 = (_Float16)e0, h1 = (_Float16)e1;
    embHp[base + jb]     = h0;
    embHp[base + jb + 4] = h1;
    embLp[base + jb]     = (_Float16)(e0 - (float)h0);
    embLp[base + jb + 4] = (_Float16)(e1 - (float)h1);
  }
}

// Conv GEMM via fp16-split MFMA: h[bg][t][o] = sum_k x[b,t,g*256+k]*w[g*256+o,k]
// 512 blocks = 32 bg x 16 t-tiles(128). Wave: 32t x 256o, acc[2][16] f32x4.
// A-frags in registers from coalesced x loads; w split hi/lo during LDS staging.
__global__ __launch_bounds__(256, 2) void k_conv2(const float* __restrict__ x,
                                                  const float* __restrict__ w,
                                                  float* __restrict__ h,
                                                  double* __restrict__ part) {
  __shared__ _Float16 BsH[4*256*8];   // 16 KB  [hgrp][o][j]
  __shared__ _Float16 BsL[4*256*8];   // 16 KB
  __shared__ double r1[4], r2[4];
  const int bid = blockIdx.x;         // 512
  const int bg = bid >> 4, tt = bid & 15;
  const int b = bg >> 1, g = bg & 1;
  const int tid = threadIdx.x;
  const int wv = tid >> 6, lane = tid & 63;
  const int l15 = tid & 15, lh = lane >> 4;
  const int t0w = (tt << 7) + (wv << 5);

  f32x4 acc[2][16];
  #pragma unroll
  for (int tf = 0; tf < 2; ++tf)
    #pragma unroll
    for (int vf = 0; vf < 16; ++vf) acc[tf][vf] = 0.0f;

  const float* wbase = w + (size_t)(g*DD + tid)*DD;

  for (int c = 0; c < 8; ++c) {
    __syncthreads();
    // stage W chunk -> fp16 hi/lo planes (thread = o row, 8 float4s)
    {
      const float* wrow = wbase + (c << 5);
      #pragma unroll
      for (int col4 = 0; col4 < 8; ++col4) {
        float4 f = *(const float4*)(wrow + (col4 << 2));
        float fe[4] = {f.x, f.y, f.z, f.w};
        half4_t vh, vl2;
        #pragma unroll
        for (int e = 0; e < 4; ++e) {
          _Float16 hh = (_Float16)fe[e];
          vh[e] = hh;
          vl2[e] = (_Float16)(fe[e] - (float)hh);
        }
        const int hgrp = col4 & 3, jo = (col4 >> 2) << 2;
        *(half4_t*)(BsH + ((((hgrp << 8) + tid) << 3) + jo)) = vh;
        *(half4_t*)(BsL + ((((hgrp << 8) + tid) << 3) + jo)) = vl2;
      }
    }
    // A-frags in registers: 2 coalesced float4 loads per t-tile
    half8 ah[2], al[2];
    #pragma unroll
    for (int tf = 0; tf < 2; ++tf) {
      const int t = t0w + (tf << 4) + l15;
      const float* src = x + ((size_t)(b*TT + t)*CC + g*DD + (c << 5) + (lh << 2));
      float4 f1 = *(const float4*)src;
      float4 f2 = *(const float4*)(src + 16);
      float fv[8] = {f1.x, f1.y, f1.z, f1.w, f2.x, f2.y, f2.z, f2.w};
      #pragma unroll
      for (int e = 0; e < 8; ++e) {
        _Float16 hh = (_Float16)fv[e];
        ah[tf][e] = hh;
        al[tf][e] = (_Float16)(fv[e] - (float)hh);
      }
    }
    __syncthreads();
    #pragma unroll
    for (int vf = 0; vf < 16; ++vf) {
      const int o = (vf << 4) + l15;
      half8 bh = *(const half8*)(BsH + (((lh << 8) + o) << 3));
      half8 bl = *(const half8*)(BsL + (((lh << 8) + o) << 3));
      #pragma unroll
      for (int tf = 0; tf < 2; ++tf) {
        acc[tf][vf] = __builtin_amdgcn_mfma_f32_16x16x32_f16(ah[tf], bh, acc[tf][vf], 0, 0, 0);
        acc[tf][vf] = __builtin_amdgcn_mfma_f32_16x16x32_f16(al[tf], bh, acc[tf][vf], 0, 0, 0);
        acc[tf][vf] = __builtin_amdgcn_mfma_f32_16x16x32_f16(ah[tf], bl, acc[tf][vf], 0, 0, 0);
      }
    }
  }

  // store h + double stats
  double s1 = 0.0, s2 = 0.0;
  {
    float* hb = h + (size_t)bg*TT*DD;
    #pragma unroll
    for (int tf = 0; tf < 2; ++tf) {
      #pragma unroll
      for (int reg = 0; reg < 4; ++reg) {
        const int t = t0w + (tf << 4) + (lh << 2) + reg;
        float* hrow = hb + (size_t)t*DD + l15;
        #pragma unroll
        for (int vf = 0; vf < 16; ++vf) {
          float v = acc[tf][vf][reg];
          hrow[vf << 4] = v;
          double dv = (double)v;
          s1 += dv; s2 += dv*dv;
        }
      }
    }
  }
  #pragma unroll
  for (int m = 32; m > 0; m >>= 1) { s1 += __shfl_down(s1, m); s2 += __shfl_down(s2, m); }
  if (lane == 0) { r1[wv] = s1; r2[wv] = s2; }
  __syncthreads();
  if (tid == 0) {
    part[(size_t)bid*2]     = r1[0] + r1[1] + r1[2] + r1[3];
    part[(size_t)bid*2 + 1] = r2[0] + r2[1] + r2[2] + r2[3];
  }
}

__global__ void k_stats(const double* __restrict__ part, float* __restrict__ musig) {
  int i = threadIdx.x;
  if (i < BB*GG) {
    double s1 = 0.0, s2 = 0.0;
    for (int r = 0; r < 16; r++) { s1 += part[(i*16 + r)*2]; s2 += part[(i*16 + r)*2 + 1]; }
    double mu  = s1 / (double)DT;
    double var = s2 / (double)DT - mu*mu;
    double rs  = 1.0 / sqrt(var + 1e-5);
    musig[i*2]     = (float)mu;
    musig[i*2 + 1] = (float)rs;
  }
}

// MFMA VQ: 128 t-rows x 320 v per block; A-frags from registers (normalize
// in-reg, exact op order); fp16-split 3-pass; candidate + exact recheck.
__global__ __launch_bounds__(256, 2) void k_vq2(const float* __restrict__ h,
                                                const float* __restrict__ musig,
                                                const float* __restrict__ gn_w,
                                                const float* __restrict__ gn_b,
                                                const _Float16* __restrict__ embH,
                                                const _Float16* __restrict__ embL,
                                                const float* __restrict__ esq,
                                                const float* __restrict__ emb,
                                                float* __restrict__ out,
                                                unsigned* __restrict__ counts,
                                                float* __restrict__ loss) {
  __shared__ __align__(16) char smem[43008];
  _Float16* BsH = (_Float16*)smem;               // [4][320][8] halfs, 20480 B
  _Float16* BsL = (_Float16*)(smem + 20480);
  float* gnws = (float*)(smem + 40960);          // 256 f
  float* gnbs = (float*)(smem + 41984);          // 256 f
  // epilogue overlay (aliases BsH region, used only after K-loop):
  float*  esqs    = (float*)smem;                // 320 f
  int*    candcnt = (int*)(smem + 1280);         // 128
  int*    bestv   = (int*)(smem + 1792);         // 128
  int*    slowl   = (int*)(smem + 2304);         // 128
  int*    nslow   = (int*)(smem + 2816);
  double* zsqs    = (double*)(smem + 2824);      // 4
  float*  scratch = (float*)(smem + 2864);       // 256 f
  unsigned short* cand = (unsigned short*)(smem + 3888);  // [128][24]
  float*  candd2  = (float*)(smem + 10032);      // 24

  const int bid = blockIdx.x;        // 512 blocks
  const int bg  = bid >> 4;
  const int t0  = (bid & 15) << 7;
  const int b = bg >> 1, g = bg & 1;
  const int tid = threadIdx.x;
  const int lane = tid & 63, wv = tid >> 6;
  const int l15 = tid & 15, lh = lane >> 4;
  const float mu = musig[bg*2], rs = musig[bg*2 + 1];
  const float* hb = h + ((size_t)bg*TT + t0)*DD;

  gnws[tid] = gn_w[g*DD + tid];
  gnbs[tid] = gn_b[g*DD + tid];

  f32x4 acc[2][20];
  #pragma unroll
  for (int tf = 0; tf < 2; ++tf)
    #pragma unroll
    for (int vf = 0; vf < 20; ++vf) acc[tf][vf] = 0.0f;

  const _Float16* gBH = embH + (size_t)(g*8)*10240;
  const _Float16* gBL = embL + (size_t)(g*8)*10240;
  const float* gwp = gn_w + g*DD;
  const float* gbp = gn_b + g*DD;

  for (int c = 0; c < 8; ++c) {
    __syncthreads();
    // stage B (straight copy, layout prebuilt in k_emb)
    {
      const uint4* sH = (const uint4*)(gBH + (size_t)c*10240);
      const uint4* sL = (const uint4*)(gBL + (size_t)c*10240);
      uint4* dH = (uint4*)BsH; uint4* dL = (uint4*)BsL;
      #pragma unroll
      for (int i = 0; i < 5; ++i) {
        dH[tid + (i << 8)] = sH[tid + (i << 8)];
        dL[tid + (i << 8)] = sL[tid + (i << 8)];
      }
    }
    // A-frags in registers: load h, normalize (exact op order), split
    const int c32 = c << 5;
    half8 ah[2], al[2];
    {
      float4 w1 = *(const float4*)(gwp + c32 + (lh << 2));
      float4 w2 = *(const float4*)(gwp + c32 + (lh << 2) + 16);
      float4 b1 = *(const float4*)(gbp + c32 + (lh << 2));
      float4 b2 = *(const float4*)(gbp + c32 + (lh << 2) + 16);
      float wv_[8] = {w1.x, w1.y, w1.z, w1.w, w2.x, w2.y, w2.z, w2.w};
      float bv_[8] = {b1.x, b1.y, b1.z, b1.w, b2.x, b2.y, b2.z, b2.w};
      #pragma unroll
      for (int tf = 0; tf < 2; ++tf) {
        const int t = (wv << 5) + (tf << 4) + l15;
        const float* src = hb + (size_t)t*DD + c32 + (lh << 2);
        float4 f1 = *(const float4*)src;
        float4 f2 = *(const float4*)(src + 16);
        float fv[8] = {f1.x, f1.y, f1.z, f1.w, f2.x, f2.y, f2.z, f2.w};
        #pragma unroll
        for (int e = 0; e < 8; ++e) {
          float z = __fmul_rn(__fsub_rn(fv[e], mu), rs);
          z = __fadd_rn(__fmul_rn(z, wv_[e]), bv_[e]);
          _Float16 zh = (_Float16)z;
          ah[tf][e] = zh;
          al[tf][e] = (_Float16)(z - (float)zh);
        }
      }
    }
    __syncthreads();
    // MFMA: wave covers rows [wv*32, wv*32+32), all 320 v
    #pragma unroll
    for (int vf = 0; vf < 20; ++vf) {
      int v = (vf << 4) + l15;
      half8 bh = *(const half8*)(BsH + ((lh*320 + v) << 3));
      half8 bl = *(const half8*)(BsL + ((lh*320 + v) << 3));
      #pragma unroll
      for (int tf = 0; tf < 2; ++tf) {
        acc[tf][vf] = __builtin_amdgcn_mfma_f32_16x16x32_f16(ah[tf], bh, acc[tf][vf], 0, 0, 0);
        acc[tf][vf] = __builtin_amdgcn_mfma_f32_16x16x32_f16(al[tf], bh, acc[tf][vf], 0, 0, 0);
        acc[tf][vf] = __builtin_amdgcn_mfma_f32_16x16x32_f16(ah[tf], bl, acc[tf][vf], 0, 0, 0);
      }
    }
  }
  __syncthreads();

  // ---- epilogue: overlay init ----
  if (tid < 160) { esqs[tid] = esq[g*VV + tid]; esqs[tid + 160] = esq[g*VV + tid + 160]; }
  if (tid < 128) { candcnt[tid] = 0; bestv[tid] = -1; }
  if (tid == 0) *nslow = 0;
  __syncthreads();

  // selection: y = esq - 2c'; candidates within MARGIN of row min
  #pragma unroll
  for (int tf = 0; tf < 2; ++tf) {
    #pragma unroll
    for (int reg = 0; reg < 4; ++reg) {
      int row = (wv << 5) + (tf << 4) + (lh << 2) + reg;
      float y[20]; float mn = 3.4e38f;
      #pragma unroll
      for (int vf = 0; vf < 20; ++vf) {
        y[vf] = fmaf(-2.0f, acc[tf][vf][reg], esqs[(vf << 4) + l15]);
        mn = fminf(mn, y[vf]);
      }
      #pragma unroll
      for (int m = 1; m < 16; m <<= 1) mn = fminf(mn, __shfl_xor(mn, m));
      float thr = mn + MARGIN;
      #pragma unroll
      for (int vf = 0; vf < 20; ++vf) {
        if (y[vf] <= thr) {
          int pos = atomicAdd(&candcnt[row], 1);
          if (pos < 24) cand[row*24 + pos] = (unsigned short)((vf << 4) + l15);
        }
      }
    }
  }
  __syncthreads();
  if (tid < 128) {
    int cnt = candcnt[tid];
    if (cnt == 1) bestv[tid] = cand[tid*24];
    else { int p = atomicAdd(nslow, 1); slowl[p] = tid; }
  }
  __syncthreads();

  // slow path: exact re-score (bit-identical arithmetic to round-2 kernel)
  const int ns = *nslow;
  for (int i = 0; i < ns; ++i) {
    const int row = slowl[i];
    float hv = hb[(size_t)row*DD + tid];
    float z = __fmul_rn(__fsub_rn(hv, mu), rs);
    z = __fadd_rn(__fmul_rn(z, gnws[tid]), gnbs[tid]);
    scratch[tid] = z;
    double q = (double)z * (double)z;
    #pragma unroll
    for (int m = 32; m > 0; m >>= 1) q += __shfl_down(q, m);
    if (lane == 0) zsqs[wv] = q;
    __syncthreads();
    const float ze2f = (float)(zsqs[0] + zsqs[1] + zsqs[2] + zsqs[3]);
    const int cnt = candcnt[row];
    if (cnt <= 24) {
      if (tid < cnt) {
        int v = cand[row*24 + tid];
        float cc = 0.0f;
        const float* ep = emb + ((size_t)v*GG + g)*DD;
        for (int d = 0; d < DD; ++d) cc = fmaf(scratch[d], ep[d], cc);
        candd2[tid] = __fadd_rn(__fsub_rn(ze2f, __fmul_rn(2.0f, cc)), esqs[v]);
      }
      __syncthreads();
      if (tid == 0) {
        float bd = 3.4e38f; int bv = 0x7fffffff;
        for (int ci = 0; ci < cnt; ++ci) {
          int v = cand[row*24 + ci]; float d2 = candd2[ci];
          if (d2 < bd || (d2 == bd && v < bv)) { bd = d2; bv = v; }
        }
        bestv[row] = bv;
      }
    } else {
      if (tid == 0) {  // overflow fallback (effectively unreachable)
        float bd = 3.4e38f; int bv = 0x7fffffff;
        for (int v = 0; v < VV; ++v) {
          float cc = 0.0f;
          const float* ep = emb + ((size_t)v*GG + g)*DD;
          for (int d = 0; d < DD; ++d) cc = fmaf(scratch[d], ep[d], cc);
          float d2 = __fadd_rn(__fsub_rn(ze2f, __fmul_rn(2.0f, cc)), esqs[v]);
          if (d2 < bd) { bd = d2; bv = v; }
        }
        bestv[row] = bv;
      }
    }
    __syncthreads();
  }

  if (tid < 128) atomicAdd(&counts[g*VV + bestv[tid]], 1u);

  // x_out = selected embedding; loss partial
  float lp = 0.0f;
  float* ob = out + (size_t)(b*TT + t0)*CC + g*DD + tid;
  const float gw = gnws[tid], gb2 = gnbs[tid];
  for (int r = 0; r < 128; ++r) {
    int v = bestv[r];
    float e = emb[((size_t)v*GG + g)*DD + tid];
    float hv = hb[(size_t)r*DD + tid];
    float z = __fmul_rn(__fsub_rn(hv, mu), rs);
    z = __fadd_rn(__fmul_rn(z, gw), gb2);
    float df = e - z;
    lp = fmaf(df, df, lp);
    ob[(size_t)r*CC] = e;
  }
  #pragma unroll
  for (int m = 32; m > 0; m >>= 1) lp += __shfl_down(lp, m);
  if (lane == 0) scratch[wv] = lp;
  __syncthreads();
  if (tid == 0) atomicAdd(loss, scratch[0] + scratch[1] + scratch[2] + scratch[3]);
}

__global__ __launch_bounds__(256) void k_final(const unsigned* __restrict__ counts,
                                               const float* __restrict__ loss,
                                               float* __restrict__ out) {
  __shared__ float sd[256];
  int tid = threadIdx.x;
  float perp = 0.0f;
  for (int g = 0; g < GG; g++) {
    float p1 = 0.0f;
    for (int v = tid; v < VV; v += 256) {
      float p = (float)counts[g*VV + v] / 32768.0f;
      p1 += p * logf(p + 1e-7f);
    }
    sd[tid] = p1;
    __syncthreads();
    for (int s = 128; s > 0; s >>= 1) {
      if (tid < s) sd[tid] += sd[tid + s];
      __syncthreads();
    }
    if (tid == 0) perp += expf(-sd[0]);
    __syncthreads();
  }
  if (tid == 0) {
    out[NOUT]     = 1.25f * (*loss) / (float)NOUT;
    out[NOUT + 1] = perp;
  }
}

extern "C" void kernel_launch(void* const* d_in, const int* in_sizes, int n_in,
                              void* d_out, int out_size, void* d_ws, size_t ws_size,
                              hipStream_t stream) {
  const float* x   = (const float*)d_in[0];
  const float* cw  = (const float*)d_in[1];
  const float* gnw = (const float*)d_in[2];
  const float* gnb = (const float*)d_in[3];
  const float* emb = (const float*)d_in[4];
  float* out = (float*)d_out;
  char* ws = (char*)d_ws;
  float*     h      = (float*)(ws + OFF_H);
  double*    part   = (double*)(ws + OFF_PART);
  float*     musig  = (float*)(ws + OFF_MUSIG);
  float*     esq    = (float*)(ws + OFF_ESQ);
  unsigned*  counts = (unsigned*)(ws + OFF_CNT);
  float*     loss   = (float*)(ws + OFF_LOSS);
  _Float16*  embH   = (_Float16*)(ws + OFF_EMBH);
  _Float16*  embL   = (_Float16*)(ws + OFF_EMBL);

  hipLaunchKernelGGL(k_emb,   dim3(41),   dim3(256), 0, stream, emb, embH, embL, esq, counts, loss);
  hipLaunchKernelGGL(k_conv2, dim3(512),  dim3(256), 0, stream, x, cw, h, part);
  hipLaunchKernelGGL(k_stats, dim3(1),    dim3(32),  0, stream, part, musig);
  hipLaunchKernelGGL(k_vq2,   dim3(512),  dim3(256), 0, stream,
                     h, musig, gnw, gnb, embH, embL, esq, emb, out, counts, loss);
  hipLaunchKernelGGL(k_final, dim3(1),    dim3(256), 0, stream, counts, loss, out);
}